// Round 1
// baseline (542.533 us; speedup 1.0000x reference)
//
#include <hip/hip_runtime.h>

#define IN_F   4096
#define OUT_F  4096
#define N_TOK  8192
#define NW     (OUT_F * IN_F)          // 16777216 weight elements
#define SEL_TARGET 8388608u            // 0-based ascending index of kth (= NW - MAX_ITER)

typedef unsigned int  u32;
typedef unsigned short u16;

typedef __bf16 bf16x8 __attribute__((ext_vector_type(8)));
typedef float  f32x4  __attribute__((ext_vector_type(4)));

// ---------- helpers ----------
__device__ inline u16 f2bf_rne(float f) {
    u32 u = __float_as_uint(f);
    u32 r = (u + 0x7fffu + ((u >> 16) & 1u)) >> 16;
    return (u16)r;
}

// ---------- radix-select histograms ----------
// PASS 1: bin = key >> 20          (2048 bins, no prefix)
// PASS 2: key>>20 == scal[0], bin = (key>>10) & 1023
// PASS 3: key>>10 == scal[0], bin = key & 1023
template <int PASS>
__global__ void hist_kernel(const uint4* __restrict__ wb,
                            u32* __restrict__ hist,
                            const u32* __restrict__ scal) {
    constexpr int NB = (PASS == 1) ? 2048 : 1024;
    __shared__ u32 lh[NB];
    for (int i = threadIdx.x; i < NB; i += blockDim.x) lh[i] = 0;
    u32 pfx = (PASS == 1) ? 0u : scal[0];
    __syncthreads();

    const int nvec = NW / 4;
    const int stride = gridDim.x * blockDim.x;
    for (int i = blockIdx.x * blockDim.x + threadIdx.x; i < nvec; i += stride) {
        uint4 v = wb[i];
        u32 k[4] = {v.x & 0x7fffffffu, v.y & 0x7fffffffu,
                    v.z & 0x7fffffffu, v.w & 0x7fffffffu};
        #pragma unroll
        for (int j = 0; j < 4; j++) {
            if (PASS == 1) {
                atomicAdd(&lh[k[j] >> 20], 1u);
            } else if (PASS == 2) {
                if ((k[j] >> 20) == pfx) atomicAdd(&lh[(k[j] >> 10) & 1023u], 1u);
            } else {
                if ((k[j] >> 10) == pfx) atomicAdd(&lh[k[j] & 1023u], 1u);
            }
        }
    }
    __syncthreads();
    for (int i = threadIdx.x; i < NB; i += blockDim.x)
        if (lh[i]) atomicAdd(&hist[i], lh[i]);
}

template <int PASS>
__global__ void find_kernel(const u32* __restrict__ hist, u32* __restrict__ scal) {
    constexpr int NB  = (PASS == 1) ? 2048 : 1024;
    constexpr int PER = NB / 256;
    __shared__ u32 tgt_s;
    __shared__ u32 part[256];
    int t = threadIdx.x;
    if (t == 0) tgt_s = (PASS == 1) ? SEL_TARGET : scal[1];
    __syncthreads();
    u32 target = tgt_s;

    u32 loc[PER];
    u32 s = 0;
    #pragma unroll
    for (int i = 0; i < PER; i++) { loc[i] = hist[t * PER + i]; s += loc[i]; }
    part[t] = s;
    __syncthreads();
    #pragma unroll
    for (int off = 1; off < 256; off <<= 1) {
        u32 v = (t >= off) ? part[t - off] : 0u;
        __syncthreads();
        part[t] += v;
        __syncthreads();
    }
    u32 cum = (t == 0) ? 0u : part[t - 1];
    #pragma unroll
    for (int i = 0; i < PER; i++) {
        u32 h = loc[i];
        if (target >= cum && target < cum + h) {
            u32 bin = (u32)(t * PER + i);
            if (PASS == 1)      { scal[0] = bin;                       scal[1] = target - cum; }
            else if (PASS == 2) { scal[0] = (scal[0] << 10) | bin;     scal[1] = target - cum; }
            else                { scal[2] = (scal[0] << 10) | bin; }
        }
        cum += h;
    }
}

// ---------- mask + f32->bf16 conversion ----------
__global__ void convert_w_kernel(const uint4* __restrict__ wb,
                                 u16* __restrict__ w16,
                                 const u32* __restrict__ scal) {
    const u32 kth = scal[2];
    const int nvec = NW / 4;
    const int stride = gridDim.x * blockDim.x;
    for (int i = blockIdx.x * blockDim.x + threadIdx.x; i < nvec; i += stride) {
        uint4 v = wb[i];
        ushort4 o;
        o.x = ((v.x & 0x7fffffffu) >= kth) ? f2bf_rne(__uint_as_float(v.x)) : (u16)0;
        o.y = ((v.y & 0x7fffffffu) >= kth) ? f2bf_rne(__uint_as_float(v.y)) : (u16)0;
        o.z = ((v.z & 0x7fffffffu) >= kth) ? f2bf_rne(__uint_as_float(v.z)) : (u16)0;
        o.w = ((v.w & 0x7fffffffu) >= kth) ? f2bf_rne(__uint_as_float(v.w)) : (u16)0;
        *(ushort4*)&w16[(size_t)i * 4] = o;
    }
}

__global__ void convert_x_kernel(const float4* __restrict__ xb,
                                 u16* __restrict__ x16) {
    const int nvec = (N_TOK * IN_F) / 4;
    const int stride = gridDim.x * blockDim.x;
    for (int i = blockIdx.x * blockDim.x + threadIdx.x; i < nvec; i += stride) {
        float4 v = xb[i];
        ushort4 o;
        o.x = f2bf_rne(v.x);
        o.y = f2bf_rne(v.y);
        o.z = f2bf_rne(v.z);
        o.w = f2bf_rne(v.w);
        *(ushort4*)&x16[(size_t)i * 4] = o;
    }
}

// ---------- bf16 MFMA GEMM (m97 structure: 128x128 tile, BK=64) ----------
// C[t,o] = sum_k A[t,k] * B[o,k] + bias[o]
#define BM 128
#define BN 128
#define BK 64

__global__ __launch_bounds__(256) void gemm_bt(
    const u16* __restrict__ A,   // x16  [N_TOK][IN_F]
    const u16* __restrict__ B,   // w16  [OUT_F][IN_F]
    const float* __restrict__ bias,
    float* __restrict__ C) {
    constexpr int M = N_TOK, N = OUT_F, K = IN_F;
    __shared__ u16 sA[BM * BK];
    __shared__ u16 sB[BN * BK];

    const int nbx = N / BN;                       // 32
    const int bx = blockIdx.x % nbx;
    const int by = blockIdx.x / nbx;
    const int brow = by * BM, bcol = bx * BN;

    const int tid  = threadIdx.x;
    const int lane = tid & 63;
    const int wv   = tid >> 6;
    const int wr   = wv >> 1, wc = wv & 1;

    f32x4 acc[4][4];
    #pragma unroll
    for (int m = 0; m < 4; m++)
        #pragma unroll
        for (int n = 0; n < 4; n++)
            acc[m][n] = {0.f, 0.f, 0.f, 0.f};

    for (int k0 = 0; k0 < K; k0 += BK) {
        __syncthreads();
        #pragma unroll
        for (int i = 0; i < 4; i++) {
            int u   = tid + i * 256;
            int row = u >> 3;
            int kc  = (u & 7) * 8;
            const u16* ga = A + (size_t)(brow + row) * K + k0 + kc;
            const u16* gb = B + (size_t)(bcol + row) * K + k0 + kc;
            __builtin_amdgcn_global_load_lds(
                (const __attribute__((address_space(1))) unsigned int*)ga,
                (__attribute__((address_space(3))) unsigned int*)&sA[u * 8], 16, 0, 0);
            __builtin_amdgcn_global_load_lds(
                (const __attribute__((address_space(1))) unsigned int*)gb,
                (__attribute__((address_space(3))) unsigned int*)&sB[u * 8], 16, 0, 0);
        }
        __syncthreads();

        #pragma unroll
        for (int ks = 0; ks < 2; ks++) {
            bf16x8 aF[4], bF[4];
            #pragma unroll
            for (int m = 0; m < 4; m++)
                aF[m] = *(const bf16x8*)&sA[(wr * 64 + m * 16 + (lane & 15)) * BK + ks * 32 + (lane >> 4) * 8];
            #pragma unroll
            for (int n = 0; n < 4; n++)
                bF[n] = *(const bf16x8*)&sB[(wc * 64 + n * 16 + (lane & 15)) * BK + ks * 32 + (lane >> 4) * 8];
            #pragma unroll
            for (int m = 0; m < 4; m++)
                #pragma unroll
                for (int n = 0; n < 4; n++)
                    acc[m][n] = __builtin_amdgcn_mfma_f32_16x16x32_bf16(aF[m], bF[n], acc[m][n], 0, 0, 0);
        }
    }

    // epilogue: C/D layout for 16x16x32 bf16: col = lane&15, row = (lane>>4)*4 + j
    const int cr = (lane >> 4) * 4;
    const int cc = lane & 15;
    #pragma unroll
    for (int n = 0; n < 4; n++) {
        int col = bcol + wc * 64 + n * 16 + cc;
        float bv = bias[col];
        #pragma unroll
        for (int m = 0; m < 4; m++) {
            int row0 = brow + wr * 64 + m * 16 + cr;
            #pragma unroll
            for (int j = 0; j < 4; j++) {
                C[(size_t)(row0 + j) * N + col] = acc[m][n][j] + bv;
            }
        }
    }
}

// ---------- launch ----------
extern "C" void kernel_launch(void* const* d_in, const int* in_sizes, int n_in,
                              void* d_out, int out_size, void* d_ws, size_t ws_size,
                              hipStream_t stream) {
    const float* x    = (const float*)d_in[0];
    const float* w    = (const float*)d_in[1];
    const float* bias = (const float*)d_in[2];
    float* out = (float*)d_out;

    char* ws = (char*)d_ws;
    u32* hist1 = (u32*)(ws + 0);          // 2048 u32
    u32* hist2 = (u32*)(ws + 8192);       // 1024 u32
    u32* hist3 = (u32*)(ws + 12288);      // 1024 u32
    u32* scal  = (u32*)(ws + 16384);      // [0]=prefix, [1]=remaining, [2]=kth bits
    u16* w16   = (u16*)(ws + 65536);                         // 33.5 MB
    u16* x16   = (u16*)(ws + 65536 + (size_t)NW * 2);        // 67 MB

    // zero the histogram/scalar region every call (graph replays don't re-poison)
    hipMemsetAsync(ws, 0, 65536, stream);

    hist_kernel<1><<<2048, 256, 0, stream>>>((const uint4*)w, hist1, scal);
    find_kernel<1><<<1, 256, 0, stream>>>(hist1, scal);
    hist_kernel<2><<<2048, 256, 0, stream>>>((const uint4*)w, hist2, scal);
    find_kernel<2><<<1, 256, 0, stream>>>(hist2, scal);
    hist_kernel<3><<<2048, 256, 0, stream>>>((const uint4*)w, hist3, scal);
    find_kernel<3><<<1, 256, 0, stream>>>(hist3, scal);

    convert_w_kernel<<<2048, 256, 0, stream>>>((const uint4*)w, w16, scal);
    convert_x_kernel<<<2048, 256, 0, stream>>>((const float4*)x, x16);

    gemm_bt<<<2048, 256, 0, stream>>>(x16, w16, bias, out);
}

// Round 2
// 401.901 us; speedup vs baseline: 1.3499x; 1.3499x over previous
//
#include <hip/hip_runtime.h>

#define IN_F   4096
#define OUT_F  4096
#define N_TOK  8192
#define NW     (OUT_F * IN_F)          // 16777216 weight elements
#define SEL_TARGET 8388608u            // 0-based ascending index of kth (= NW - MAX_ITER)

typedef unsigned int  u32;
typedef unsigned short u16;

typedef __bf16 bf16x8 __attribute__((ext_vector_type(8)));
typedef float  f32x4  __attribute__((ext_vector_type(4)));

// ---------- helpers ----------
__device__ inline u16 f2bf_rne(float f) {
    u32 u = __float_as_uint(f);
    u32 r = (u + 0x7fffu + ((u >> 16) & 1u)) >> 16;
    return (u16)r;
}

// ---------- radix-select histograms ----------
template <int PASS>
__global__ void hist_kernel(const uint4* __restrict__ wb,
                            u32* __restrict__ hist,
                            const u32* __restrict__ scal) {
    constexpr int NB = (PASS == 1) ? 2048 : 1024;
    __shared__ u32 lh[NB];
    for (int i = threadIdx.x; i < NB; i += blockDim.x) lh[i] = 0;
    u32 pfx = (PASS == 1) ? 0u : scal[0];
    __syncthreads();

    const int nvec = NW / 4;
    const int stride = gridDim.x * blockDim.x;
    for (int i = blockIdx.x * blockDim.x + threadIdx.x; i < nvec; i += stride) {
        uint4 v = wb[i];
        u32 k[4] = {v.x & 0x7fffffffu, v.y & 0x7fffffffu,
                    v.z & 0x7fffffffu, v.w & 0x7fffffffu};
        #pragma unroll
        for (int j = 0; j < 4; j++) {
            if (PASS == 1) {
                atomicAdd(&lh[k[j] >> 20], 1u);
            } else if (PASS == 2) {
                if ((k[j] >> 20) == pfx) atomicAdd(&lh[(k[j] >> 10) & 1023u], 1u);
            } else {
                if ((k[j] >> 10) == pfx) atomicAdd(&lh[k[j] & 1023u], 1u);
            }
        }
    }
    __syncthreads();
    for (int i = threadIdx.x; i < NB; i += blockDim.x)
        if (lh[i]) atomicAdd(&hist[i], lh[i]);
}

template <int PASS>
__global__ void find_kernel(const u32* __restrict__ hist, u32* __restrict__ scal) {
    constexpr int NB  = (PASS == 1) ? 2048 : 1024;
    constexpr int PER = NB / 256;
    __shared__ u32 tgt_s;
    __shared__ u32 part[256];
    int t = threadIdx.x;
    if (t == 0) tgt_s = (PASS == 1) ? SEL_TARGET : scal[1];
    __syncthreads();
    u32 target = tgt_s;

    u32 loc[PER];
    u32 s = 0;
    #pragma unroll
    for (int i = 0; i < PER; i++) { loc[i] = hist[t * PER + i]; s += loc[i]; }
    part[t] = s;
    __syncthreads();
    #pragma unroll
    for (int off = 1; off < 256; off <<= 1) {
        u32 v = (t >= off) ? part[t - off] : 0u;
        __syncthreads();
        part[t] += v;
        __syncthreads();
    }
    u32 cum = (t == 0) ? 0u : part[t - 1];
    #pragma unroll
    for (int i = 0; i < PER; i++) {
        u32 h = loc[i];
        if (target >= cum && target < cum + h) {
            u32 bin = (u32)(t * PER + i);
            if (PASS == 1)      { scal[0] = bin;                       scal[1] = target - cum; }
            else if (PASS == 2) { scal[0] = (scal[0] << 10) | bin;     scal[1] = target - cum; }
            else                { scal[2] = (scal[0] << 10) | bin; }
        }
        cum += h;
    }
}

// ---------- mask + f32->bf16 conversion ----------
__global__ void convert_w_kernel(const uint4* __restrict__ wb,
                                 u16* __restrict__ w16,
                                 const u32* __restrict__ scal) {
    const u32 kth = scal[2];
    const int nvec = NW / 4;
    const int stride = gridDim.x * blockDim.x;
    for (int i = blockIdx.x * blockDim.x + threadIdx.x; i < nvec; i += stride) {
        uint4 v = wb[i];
        ushort4 o;
        o.x = ((v.x & 0x7fffffffu) >= kth) ? f2bf_rne(__uint_as_float(v.x)) : (u16)0;
        o.y = ((v.y & 0x7fffffffu) >= kth) ? f2bf_rne(__uint_as_float(v.y)) : (u16)0;
        o.z = ((v.z & 0x7fffffffu) >= kth) ? f2bf_rne(__uint_as_float(v.z)) : (u16)0;
        o.w = ((v.w & 0x7fffffffu) >= kth) ? f2bf_rne(__uint_as_float(v.w)) : (u16)0;
        *(ushort4*)&w16[(size_t)i * 4] = o;
    }
}

__global__ void convert_x_kernel(const float4* __restrict__ xb,
                                 u16* __restrict__ x16) {
    const int nvec = (N_TOK * IN_F) / 4;
    const int stride = gridDim.x * blockDim.x;
    for (int i = blockIdx.x * blockDim.x + threadIdx.x; i < nvec; i += stride) {
        float4 v = xb[i];
        ushort4 o;
        o.x = f2bf_rne(v.x);
        o.y = f2bf_rne(v.y);
        o.z = f2bf_rne(v.z);
        o.w = f2bf_rne(v.w);
        *(ushort4*)&x16[(size_t)i * 4] = o;
    }
}

// ---------- 256x256 8-phase bf16 MFMA GEMM (m201-style template) ----------
// C[t,o] = sum_k A[t,k] * B[o,k] + bias[o];  A = x16 [8192][4096], B = w16 [4096][4096]
#define BK 64
#define NT (IN_F / BK)   // 64 K-tiles

// LDS u16-index slot bases: A = 4 slots of 8192 u16 (16 KB), then B.
#define ASLOT(buf, ks) (((buf) * 2 + (ks)) * 8192)
#define BSLOT(buf, ks) (32768 + ((buf) * 2 + (ks)) * 8192)

#define VMCNT(n) asm volatile("s_waitcnt vmcnt(" #n ")" ::: "memory")
#define LGKM0    asm volatile("s_waitcnt lgkmcnt(0)" ::: "memory")
#define SB0      __builtin_amdgcn_sched_barrier(0)
#define BARR()   __builtin_amdgcn_s_barrier()

__global__ __launch_bounds__(512, 2) void gemm8p(
    const u16* __restrict__ A,
    const u16* __restrict__ B,
    const float* __restrict__ bias,
    float* __restrict__ C) {
    __shared__ u16 lds[65536];   // 128 KiB

    const int tid  = threadIdx.x;
    const int lane = tid & 63;
    const int ln15 = lane & 15;
    const int l16  = lane >> 4;
    const int wv   = tid >> 6;       // 0..7
    const int wr   = wv >> 2;        // 0..1  (M)
    const int wc   = wv & 3;         // 0..3  (N)
    const int wrow = wr * 128;
    const int wcol = wc * 64;

    // XCD-bijective block swizzle (512 blocks, 512 % 8 == 0)
    const int bid = blockIdx.x;
    const int swz = (bid & 7) * 64 + (bid >> 3);
    const int by  = swz >> 4;        // 0..31
    const int bx  = swz & 15;        // 0..15
    const int arow = by * 256;
    const int brow = bx * 256;

    f32x4 acc[8][4];
    #pragma unroll
    for (int m = 0; m < 8; m++)
        #pragma unroll
        for (int n = 0; n < 4; n++)
            acc[m][n] = {0.f, 0.f, 0.f, 0.f};

    // Stage one half-tile (256 rows x 32 cols bf16 = 16 KB): linear LDS dest,
    // inverse-swizzled global source (chunk ^= (row>>1)&3), 2 x gload_lds(16B)/thread.
    #define STAGE(G, rowbase, kt, ks, slot) do {                                        \
        _Pragma("unroll")                                                               \
        for (int i_ = 0; i_ < 2; i_++) {                                                \
            int q_  = tid + i_ * 512;                                                   \
            int r_  = q_ >> 2;                                                          \
            int cs_ = (q_ & 3) ^ ((r_ >> 1) & 3);                                       \
            const u16* src_ = (G) + (size_t)((rowbase) + r_) * IN_F                     \
                              + (kt) * BK + (ks) * 32 + cs_ * 8;                        \
            __builtin_amdgcn_global_load_lds(                                           \
                (const __attribute__((address_space(1))) unsigned int*)src_,            \
                (__attribute__((address_space(3))) unsigned int*)&lds[(slot) + q_ * 8], \
                16, 0, 0);                                                              \
        } } while (0)

    #define READ_A(mh, ks, buf) do {                                                    \
        _Pragma("unroll")                                                               \
        for (int i_ = 0; i_ < 4; i_++) {                                                \
            int row_ = wrow + ((mh) * 4 + i_) * 16 + ln15;                              \
            int cc_  = l16 ^ ((row_ >> 1) & 3);                                         \
            aF[i_] = *(const bf16x8*)&lds[ASLOT(buf, ks) + row_ * 32 + cc_ * 8];        \
        } } while (0)

    #define READ_B(ks, buf) do {                                                       \
        _Pragma("unroll")                                                               \
        for (int i_ = 0; i_ < 4; i_++) {                                                \
            int row_ = wcol + i_ * 16 + ln15;                                           \
            int cc_  = l16 ^ ((row_ >> 1) & 3);                                         \
            bF[i_] = *(const bf16x8*)&lds[BSLOT(buf, ks) + row_ * 32 + cc_ * 8];        \
        } } while (0)

    #define MFMAQ(mh) do {                                                              \
        __builtin_amdgcn_s_setprio(1);                                                  \
        _Pragma("unroll")                                                               \
        for (int i_ = 0; i_ < 4; i_++)                                                  \
            _Pragma("unroll")                                                           \
            for (int n_ = 0; n_ < 4; n_++)                                              \
                acc[(mh) * 4 + i_][n_] = __builtin_amdgcn_mfma_f32_16x16x32_bf16(       \
                    aF[i_], bF[n_], acc[(mh) * 4 + i_][n_], 0, 0, 0);                   \
        __builtin_amdgcn_s_setprio(0);                                                  \
    } while (0)

    // ---- prologue: stage tile0 (4 halves) + tile1 (3 halves), per template ----
    STAGE(B, brow, 0, 0, BSLOT(0, 0));
    STAGE(A, arow, 0, 0, ASLOT(0, 0));
    STAGE(B, brow, 0, 1, BSLOT(0, 1));
    STAGE(A, arow, 0, 1, ASLOT(0, 1));
    VMCNT(4);
    STAGE(B, brow, 1, 0, BSLOT(1, 0));
    STAGE(A, arow, 1, 0, ASLOT(1, 0));
    STAGE(B, brow, 1, 1, BSLOT(1, 1));
    VMCNT(6);            // tile 0 fully landed; 3 half-tiles (6 loads) in flight
    BARR();

    bf16x8 aF[4], bF[4];

    #pragma unroll 1
    for (int it = 0; it < NT / 2; it++) {
        const int t0 = 2 * it;
        const int ka = t0 + 1;                          // <= NT-1 always
        const int kb = (t0 + 2 < NT) ? t0 + 2 : NT - 1; // clamp keeps loads in-bounds
        const int kc = (t0 + 3 < NT) ? t0 + 3 : NT - 1;

        // ---- tile t0 (buf 0) ----
        // P1: quadrant (m0-3, ks0)
        READ_A(0, 0, 0); READ_B(0, 0);
        STAGE(A, arow, ka, 1, ASLOT(1, 1));             // (t0+1).A-k1
        BARR(); LGKM0; SB0; MFMAQ(0); SB0; BARR();
        // P2: (m4-7, ks0)
        READ_A(1, 0, 0);
        STAGE(B, brow, kb, 0, BSLOT(0, 0));             // (t0+2).B-k0
        BARR(); LGKM0; SB0; MFMAQ(1); SB0; BARR();
        // P3: (m0-3, ks1)
        READ_A(0, 1, 0); READ_B(1, 0);
        STAGE(A, arow, kb, 0, ASLOT(0, 0));             // (t0+2).A-k0
        BARR(); LGKM0; SB0; MFMAQ(0); SB0; BARR();
        // P4: (m4-7, ks1)
        READ_A(1, 1, 0);
        STAGE(B, brow, kb, 1, BSLOT(0, 1));             // (t0+2).B-k1
        VMCNT(6);                                       // tile t0+1 fully landed
        BARR(); LGKM0; SB0; MFMAQ(1); SB0; BARR();

        // ---- tile t0+1 (buf 1) ----
        // P5
        READ_A(0, 0, 1); READ_B(0, 1);
        STAGE(A, arow, kb, 1, ASLOT(0, 1));             // (t1+1).A-k1
        BARR(); LGKM0; SB0; MFMAQ(0); SB0; BARR();
        // P6
        READ_A(1, 0, 1);
        STAGE(B, brow, kc, 0, BSLOT(1, 0));             // (t1+2).B-k0
        BARR(); LGKM0; SB0; MFMAQ(1); SB0; BARR();
        // P7
        READ_A(0, 1, 1); READ_B(1, 1);
        STAGE(A, arow, kc, 0, ASLOT(1, 0));             // (t1+2).A-k0
        BARR(); LGKM0; SB0; MFMAQ(0); SB0; BARR();
        // P8
        READ_A(1, 1, 1);
        STAGE(B, brow, kc, 1, BSLOT(1, 1));             // (t1+2).B-k1
        VMCNT(6);                                       // tile t0+2 fully landed
        BARR(); LGKM0; SB0; MFMAQ(1); SB0; BARR();
    }
    VMCNT(0);   // drain trailing prefetches before epilogue

    // ---- epilogue: C/D layout col = lane&15, row = (lane>>4)*4 + j ----
    const int cr = l16 * 4;
    #pragma unroll
    for (int n = 0; n < 4; n++) {
        int col = brow + wcol + n * 16 + ln15;
        float bv = bias[col];
        #pragma unroll
        for (int m = 0; m < 8; m++) {
            int r0 = arow + wrow + m * 16 + cr;
            #pragma unroll
            for (int j = 0; j < 4; j++) {
                C[(size_t)(r0 + j) * OUT_F + col] = acc[m][n][j] + bv;
            }
        }
    }
}

// ---------- launch ----------
extern "C" void kernel_launch(void* const* d_in, const int* in_sizes, int n_in,
                              void* d_out, int out_size, void* d_ws, size_t ws_size,
                              hipStream_t stream) {
    const float* x    = (const float*)d_in[0];
    const float* w    = (const float*)d_in[1];
    const float* bias = (const float*)d_in[2];
    float* out = (float*)d_out;

    char* ws = (char*)d_ws;
    u32* hist1 = (u32*)(ws + 0);          // 2048 u32
    u32* hist2 = (u32*)(ws + 8192);       // 1024 u32
    u32* hist3 = (u32*)(ws + 12288);      // 1024 u32
    u32* scal  = (u32*)(ws + 16384);      // [0]=prefix, [1]=remaining, [2]=kth bits
    u16* w16   = (u16*)(ws + 65536);                         // 33.5 MB
    u16* x16   = (u16*)(ws + 65536 + (size_t)NW * 2);        // 67 MB

    hipMemsetAsync(ws, 0, 65536, stream);

    hist_kernel<1><<<2048, 256, 0, stream>>>((const uint4*)w, hist1, scal);
    find_kernel<1><<<1, 256, 0, stream>>>(hist1, scal);
    hist_kernel<2><<<2048, 256, 0, stream>>>((const uint4*)w, hist2, scal);
    find_kernel<2><<<1, 256, 0, stream>>>(hist2, scal);
    hist_kernel<3><<<2048, 256, 0, stream>>>((const uint4*)w, hist3, scal);
    find_kernel<3><<<1, 256, 0, stream>>>(hist3, scal);

    convert_w_kernel<<<2048, 256, 0, stream>>>((const uint4*)w, w16, scal);
    convert_x_kernel<<<2048, 256, 0, stream>>>((const float4*)x, x16);

    gemm8p<<<512, 512, 0, stream>>>(x16, w16, bias, out);
}